// Round 6
// baseline (119.117 us; speedup 1.0000x reference)
//
#include <hip/hip_runtime.h>
#include <hip/hip_bf16.h>

#define DEV static __device__ __forceinline__

typedef __attribute__((ext_vector_type(8))) short bf16x8;
typedef __attribute__((ext_vector_type(4))) float f32x4;

DEV float sigm(float x) { return 1.0f / (1.0f + __expf(-x)); }

DEV unsigned pack2bf(float a, float b) {
    unsigned ua = __float_as_uint(a); ua = (ua + 0x7FFF + ((ua >> 16) & 1)) >> 16;
    unsigned ub = __float_as_uint(b); ub = (ub + 0x7FFF + ((ub >> 16) & 1)) >> 16;
    return ua | (ub << 16);
}
DEV unsigned mulbf2(unsigned u, float d) {
    float lo = __uint_as_float(u << 16) * d;
    float hi = __uint_as_float(u & 0xffff0000u) * d;
    return pack2bf(lo, hi);
}

// B=2, N=256, Nh=192, D=128, R=20.  kappa = j*24 + r (r: 0-19 rbf, 20 bias, 21-23 pad), K=6144.

// Kernel A: s_all = where(is_h, h_emb, pad(s_heavy)); x = glu(rmsnorm(s_all)) @ W_i2 + b_i2
__global__ __launch_bounds__(256) void kA(
    const float* __restrict__ s_heavy, const int* __restrict__ is_h,
    const float* __restrict__ h_emb, const float* __restrict__ norm1_w,
    const float* __restrict__ W_i1, const float* __restrict__ b_i1,
    const float* __restrict__ W_i2, const float* __restrict__ b_i2,
    float* __restrict__ s_all, float* __restrict__ x)
{
    const int bi = blockIdx.x;
    const int b = bi >> 8, i = bi & 255;
    const int t = threadIdx.x;
    __shared__ float y[128];
    __shared__ float o[256];
    __shared__ float h[128];
    __shared__ float red[4];

    float s = 0.f;
    if (t < 128) {
        if (is_h[bi] != 0) s = h_emb[t];
        else if (i < 192) s = s_heavy[(b * 192 + i) * 128 + t];
        s_all[bi * 128 + t] = s;
    }
    float ss = s * s;
    #pragma unroll
    for (int off = 32; off > 0; off >>= 1) ss += __shfl_xor(ss, off, 64);
    if ((t & 63) == 0) red[t >> 6] = ss;
    __syncthreads();
    float v = (red[0] + red[1] + red[2] + red[3]) * (1.0f / 128.0f);
    float inv = rsqrtf(v + 1e-6f);
    if (t < 128) y[t] = s * inv * (1.0f + norm1_w[t]);
    __syncthreads();

    float acc = b_i1[t];
    #pragma unroll 8
    for (int k = 0; k < 128; ++k) acc += y[k] * W_i1[k * 256 + t];
    o[t] = acc;
    __syncthreads();
    if (t < 128) {
        float a = o[t], g = o[t + 128];
        h[t] = a * sigm(a) * sigm(g);
    }
    __syncthreads();
    for (int c = t; c < 384; c += 256) {
        float a2 = b_i2[c];
        #pragma unroll 8
        for (int k = 0; k < 128; ++k) a2 += h[k] * W_i2[k * 384 + c];
        x[(long)bi * 384 + c] = a2;
    }
}

// Kernel PX: blocks <512 build A0[b][i][kappa] = rbf*mask (bf16);
//            blocks >=512 build Bp[b][n][kappa] (bf16): Wf-folded B panel.
__global__ __launch_bounds__(256) void kPX(
    const float* __restrict__ rbf, const float* __restrict__ mask_ij,
    const float* __restrict__ x, const float* __restrict__ v_all,
    const float* __restrict__ W_filter, const float* __restrict__ b_filter,
    unsigned* __restrict__ A0, unsigned* __restrict__ Bp)
{
    const int blk = blockIdx.x, t = threadIdx.x;
    if (blk < 512) {
        const int b = blk >> 8, i = blk & 255, j = t;
        const long cell = (long)(b * 256 + i) * 256 + j;
        const float* rr = rbf + cell * 20;
        const float m = mask_ij[cell];
        float va[24];
        #pragma unroll
        for (int r = 0; r < 20; ++r) va[r] = rr[r] * m;
        va[20] = m; va[21] = 0.f; va[22] = 0.f; va[23] = 0.f;
        unsigned pk[12];
        #pragma unroll
        for (int k = 0; k < 12; ++k) pk[k] = pack2bf(va[2 * k], va[2 * k + 1]);
        unsigned* dst = A0 + (long)(b * 256 + i) * 3072 + j * 12;
        *(uint4*)&dst[0] = make_uint4(pk[0], pk[1], pk[2], pk[3]);
        *(uint4*)&dst[4] = make_uint4(pk[4], pk[5], pk[6], pk[7]);
        *(uint4*)&dst[8] = make_uint4(pk[8], pk[9], pk[10], pk[11]);
    } else {
        const int blk2 = blk - 512;
        const int b = blk2 / 40, ct = blk2 % 40;
        const int n0 = ct * 16;
        int xcol0, r3 = 0; bool usev = false;
        if (n0 < 128) { xcol0 = n0; }
        else if (n0 < 512) { r3 = (n0 - 128) >> 7; xcol0 = 256 + ((n0 - 128) & 127); usev = true; }
        else { xcol0 = 128 + (n0 - 512); }
        __shared__ float wf_l[16][24];
        __shared__ float xv_l[16][17];
        for (int u = t; u < 384; u += 256) {
            int cc = u / 24, r = u % 24;
            float w = 0.f;
            if (r < 20) w = W_filter[r * 384 + xcol0 + cc];
            else if (r == 20) w = b_filter[xcol0 + cc];
            wf_l[cc][r] = w;
        }
        __syncthreads();
        for (int jc = 0; jc < 16; ++jc) {
            {
                const int jj = t >> 4, cc = t & 15;
                const int j = jc * 16 + jj;
                float vv = x[(long)(b * 256 + j) * 384 + xcol0 + cc];
                if (usev) vv *= v_all[((long)(b * 256 + j) * 3 + r3) * 128 + (xcol0 - 256) + cc];
                xv_l[jj][cc] = vv;
            }
            __syncthreads();
            {
                const int cc = t >> 4, jj = t & 15;
                const int j = jc * 16 + jj;
                const float xvj = xv_l[jj][cc];
                unsigned pk[12];
                #pragma unroll
                for (int k = 0; k < 12; ++k)
                    pk[k] = pack2bf(wf_l[cc][2 * k] * xvj, wf_l[cc][2 * k + 1] * xvj);
                unsigned* dst = Bp + (long)(b * 640 + n0 + cc) * 3072 + j * 12;
                *(uint4*)&dst[0] = make_uint4(pk[0], pk[1], pk[2], pk[3]);
                *(uint4*)&dst[4] = make_uint4(pk[4], pk[5], pk[6], pk[7]);
                *(uint4*)&dst[8] = make_uint4(pk[8], pk[9], pk[10], pk[11]);
            }
            __syncthreads();
        }
    }
}

// Kernel G: GEMM  P[ks][b][i][n] partial = A(0 or A0*dir_r3)[i,kappa_slice] @ Bp[n,kappa_slice]
// grid 224 = 2b x 4 Mt x 7 Nt x 4 Ks; block 256 thr = 4 waves of 32x64; tile 64x128, K-slice 1536.
__global__ __launch_bounds__(256, 4) void kG(
    const unsigned* __restrict__ A0, const unsigned* __restrict__ Bp,
    const float* __restrict__ dir_ij, float* __restrict__ P)
{
    int blk = blockIdx.x;
    const int ks = blk & 3; blk >>= 2;
    const int nt = blk % 7; blk /= 7;
    const int mt = blk & 3; const int b = blk >> 2;
    const int i0 = mt * 64;
    const bool r3kind = (nt >= 4);
    const int r3 = r3kind ? (nt - 4) : 0;
    const int bpcol0 = r3kind ? 512 : nt * 128;
    const int pcol0 = r3kind ? (512 + r3 * 128) : nt * 128;
    const int t = threadIdx.x, lane = t & 63, wv = t >> 6;
    const int g = lane >> 4, l16 = lane & 15;
    const int wr = wv >> 1, wc = wv & 1;

    __shared__ short A_lds[64 * 104];
    __shared__ short B_lds[128 * 104];

    f32x4 acc[2][4];
    #pragma unroll
    for (int rt = 0; rt < 2; ++rt)
        #pragma unroll
        for (int ct = 0; ct < 4; ++ct) acc[rt][ct] = {0.f, 0.f, 0.f, 0.f};

    const int kbase = ks * 1536;
    for (int s = 0; s < 16; ++s) {
        const int k0 = kbase + s * 96;
        #pragma unroll
        for (int u = t; u < 768; u += 256) {          // A tile: 64 rows x 96 kappa
            const int row = u / 12, seg = u % 12;
            uint4 w = *(const uint4*)&A0[(long)(b * 256 + i0 + row) * 3072 + (k0 >> 1) + seg * 4];
            if (r3kind) {
                const int kg = k0 + seg * 8;
                const int j = kg / 24;
                const float dv = dir_ij[((long)(b * 256 + i0 + row) * 256 + j) * 3 + r3];
                w.x = mulbf2(w.x, dv); w.y = mulbf2(w.y, dv);
                w.z = mulbf2(w.z, dv); w.w = mulbf2(w.w, dv);
            }
            *(uint4*)&A_lds[row * 104 + seg * 8] = w;
        }
        #pragma unroll
        for (int u = t; u < 1536; u += 256) {         // B tile: 128 cols x 96 kappa
            const int col = u / 12, seg = u % 12;
            uint4 w = *(const uint4*)&Bp[(long)(b * 640 + bpcol0 + col) * 3072 + (k0 >> 1) + seg * 4];
            *(uint4*)&B_lds[col * 104 + seg * 8] = w;
        }
        __syncthreads();
        #pragma unroll
        for (int k3 = 0; k3 < 3; ++k3) {
            bf16x8 af[2], bf[4];
            #pragma unroll
            for (int rt = 0; rt < 2; ++rt)
                af[rt] = *(const bf16x8*)&A_lds[(wr * 32 + rt * 16 + l16) * 104 + k3 * 32 + g * 8];
            #pragma unroll
            for (int ct = 0; ct < 4; ++ct)
                bf[ct] = *(const bf16x8*)&B_lds[(wc * 64 + ct * 16 + l16) * 104 + k3 * 32 + g * 8];
            #pragma unroll
            for (int rt = 0; rt < 2; ++rt)
                #pragma unroll
                for (int ct = 0; ct < 4; ++ct)
                    acc[rt][ct] = __builtin_amdgcn_mfma_f32_16x16x32_bf16(af[rt], bf[ct], acc[rt][ct], 0, 0, 0);
        }
        __syncthreads();
    }

    float* Pb = P + (long)((ks * 2 + b) * 256) * 896;
    #pragma unroll
    for (int rt = 0; rt < 2; ++rt)
        #pragma unroll
        for (int ct = 0; ct < 4; ++ct)
            #pragma unroll
            for (int e = 0; e < 4; ++e) {
                const int i = i0 + wr * 32 + rt * 16 + g * 4 + e;
                const int n = pcol0 + wc * 64 + ct * 16 + l16;
                Pb[(long)i * 896 + n] = acc[rt][ct][e];
            }
}

// Kernel C2: paired mixing. Two rows per block (512 thr), sums split-K partials.
__global__ __launch_bounds__(512) void kC2(
    const float* __restrict__ W_mu, const float* __restrict__ norm2_w,
    const float* __restrict__ W_m1, const float* __restrict__ b_m1,
    const float* __restrict__ W_m2, const float* __restrict__ b_m2,
    const float* __restrict__ s_all, const float* __restrict__ v_all,
    const float* __restrict__ P,
    float* __restrict__ q_out, float* __restrict__ mu_out)
{
    const int h = threadIdx.x >> 8, tt = threadIdx.x & 255;
    const int bi = blockIdx.x * 2 + h;
    const int b = bi >> 8, i = bi & 255;
    __shared__ float mu_s[2][384];
    __shared__ float muV[2][384], muW[2][384];
    __shared__ float ctxl[2][256];
    __shared__ float o[2][256];
    __shared__ float hh[2][128];
    __shared__ float x2s[2][384];
    __shared__ float red[2][4];

    const float* Pb0 = P + ((long)b * 256 + i) * 896;
    const long kst = (long)2 * 256 * 896;
    for (int idx = tt; idx < 384; idx += 256) {
        float dm = 0.f;
        #pragma unroll
        for (int ks = 0; ks < 4; ++ks)
            dm += Pb0[ks * kst + 128 + idx] + Pb0[ks * kst + 512 + idx];
        mu_s[h][idx] = v_all[(long)bi * 384 + idx] + dm;
    }
    float qv = 0.f;
    if (tt < 128) {
        float dq = 0.f;
        #pragma unroll
        for (int ks = 0; ks < 4; ++ks) dq += Pb0[ks * kst + tt];
        qv = s_all[bi * 128 + tt] + dq;
    }
    __syncthreads();

    float m0 = 0.f, m1 = 0.f, m2 = 0.f;
    #pragma unroll 8
    for (int k = 0; k < 128; ++k) {
        float ww = W_mu[k * 256 + tt];
        m0 += mu_s[h][k] * ww;
        m1 += mu_s[h][128 + k] * ww;
        m2 += mu_s[h][256 + k] * ww;
    }
    if (tt < 128) { muV[h][tt] = m0; muV[h][128 + tt] = m1; muV[h][256 + tt] = m2; }
    else { int d2 = tt - 128; muW[h][d2] = m0; muW[h][128 + d2] = m1; muW[h][256 + d2] = m2; }

    float ss = qv * qv;
    #pragma unroll
    for (int off = 32; off > 0; off >>= 1) ss += __shfl_xor(ss, off, 64);
    if ((tt & 63) == 0) red[h][tt >> 6] = ss;
    __syncthreads();
    float mean = (red[h][0] + red[h][1] + red[h][2] + red[h][3]) * (1.0f / 128.0f);
    if (tt < 128) {
        ctxl[h][tt] = qv * rsqrtf(mean + 1e-6f) * (1.0f + norm2_w[tt]);
    } else {
        int d2 = tt - 128;
        ctxl[h][tt] = sqrtf(muV[h][d2] * muV[h][d2] + muV[h][128 + d2] * muV[h][128 + d2]
                            + muV[h][256 + d2] * muV[h][256 + d2] + 1e-6f);
    }
    __syncthreads();

    float acc = b_m1[tt];
    #pragma unroll 8
    for (int k = 0; k < 256; ++k) acc += ctxl[h][k] * W_m1[k * 256 + tt];
    o[h][tt] = acc;
    __syncthreads();
    if (tt < 128) { float a = o[h][tt], gg = o[h][tt + 128]; hh[h][tt] = a * sigm(a) * sigm(gg); }
    __syncthreads();
    for (int c = tt; c < 384; c += 256) {
        float a2 = b_m2[c];
        #pragma unroll 8
        for (int k = 0; k < 128; ++k) a2 += hh[h][k] * W_m2[k * 384 + c];
        x2s[h][c] = a2;
    }
    __syncthreads();

    if (tt < 128) {
        const int d = tt;
        float vw = muV[h][d] * muW[h][d] + muV[h][128 + d] * muW[h][128 + d]
                 + muV[h][256 + d] * muW[h][256 + d];
        if (i < 192)
            q_out[((long)b * 192 + i) * 128 + d] = qv + x2s[h][d] + x2s[h][256 + d] * vw;
        #pragma unroll
        for (int r = 0; r < 3; ++r)
            mu_out[((long)bi * 3 + r) * 128 + d] =
                mu_s[h][r * 128 + d] + x2s[h][128 + d] * muW[h][r * 128 + d];
    }
}

extern "C" void kernel_launch(void* const* d_in, const int* in_sizes, int n_in,
                              void* d_out, int out_size, void* d_ws, size_t ws_size,
                              hipStream_t stream) {
    (void)in_sizes; (void)n_in; (void)out_size;
    const float* s_heavy  = (const float*)d_in[0];
    const float* v_all    = (const float*)d_in[1];
    const float* rbf      = (const float*)d_in[2];
    const float* dir_ij   = (const float*)d_in[3];
    const float* mask_ij  = (const float*)d_in[4];
    const int*   is_h     = (const int*)d_in[5];
    const float* h_emb    = (const float*)d_in[6];
    const float* W_filter = (const float*)d_in[7];
    const float* b_filter = (const float*)d_in[8];
    const float* norm1_w  = (const float*)d_in[9];
    const float* W_i1     = (const float*)d_in[10];
    const float* b_i1     = (const float*)d_in[11];
    const float* W_i2     = (const float*)d_in[12];
    const float* b_i2     = (const float*)d_in[13];
    const float* norm2_w  = (const float*)d_in[14];
    const float* W_m1     = (const float*)d_in[15];
    const float* b_m1     = (const float*)d_in[16];
    const float* W_m2     = (const float*)d_in[17];
    const float* b_m2     = (const float*)d_in[18];
    const float* W_mu     = (const float*)d_in[19];

    // ws layout (f32 units): s_all 65536 | x 196608 | P 1835008 | A0 1572864(u32) | Bp 3932160(u32)
    const size_t need = (size_t)7602176 * 4;
    if (ws_size < need) return;  // scratch too small -> visible failure rather than OOB writes
    float* ws    = (float*)d_ws;
    float* s_all = ws;
    float* x     = ws + 65536;
    float* P     = ws + 262144;
    unsigned* A0 = (unsigned*)(ws + 2097152);
    unsigned* Bp = (unsigned*)(ws + 3670016);

    float* q_out  = (float*)d_out;               // (2,192,128)
    float* mu_out = q_out + 2 * 192 * 128;       // (2,256,3,128)

    kA<<<512, 256, 0, stream>>>(s_heavy, is_h, h_emb, norm1_w, W_i1, b_i1, W_i2, b_i2,
                                s_all, x);
    kPX<<<592, 256, 0, stream>>>(rbf, mask_ij, x, v_all, W_filter, b_filter, A0, Bp);
    kG<<<224, 256, 0, stream>>>(A0, Bp, dir_ij, P);
    kC2<<<256, 512, 0, stream>>>(W_mu, norm2_w, W_m1, b_m1, W_m2, b_m2,
                                 s_all, v_all, P, q_out, mu_out);
}